// Round 9
// baseline (859.765 us; speedup 1.0000x reference)
//
#include <hip/hip_runtime.h>
#include <hip/hip_bf16.h>

// Attention aggregator: B=8, N=2048, D=512. fp32 in, fp32 out.
// Round 9: occupancy attack. Pre-pass converts X -> bf16 in d_ws in two
// layouts (row-major Xb16 + transposed XT16): removes in-loop cvt VALU and
// the KsmT transpose scatter (1.7e7 bank conflicts in R8). Main kernel:
// QT=32, K-split 2 (wave pairs own K-halves, flash merge at end) -> grid 512
// (2 blocks/CU, 8 waves/CU vs R8's 4). PV B-frags read 16B direct from XT16
// (L2-hot). Fallback to R8 kernel if ws too small.

typedef __attribute__((ext_vector_type(8))) short short8;
typedef __attribute__((ext_vector_type(4))) short short4v;
typedef __attribute__((ext_vector_type(4))) float float4v;

#define NN 2048
#define DD 512
#define NB 8
#define NEGINF -9999999.0f

#define QT 32
#define KHALF 1024
#define KT 32
#define KSM_S 520       // Ksm row stride (shorts)
#define PB_S  40

// smem layout (bytes): Ksm [2][32*520]s @0 (66560) | Pbuf [4][16*40]s @66560
// (5120) | Msm [4][16]f @71680 (256) | Lsm @71936 (256). Merge-phase Osm
// [32][512]f overlaps Ksm @0 (65536).
#define SM_BYTES 72192
#define OFF_PBUF 66560
#define OFF_MSM  71680
#define OFF_LSM  71936

__device__ __forceinline__ short f2bf(float x) {
  union { __hip_bfloat16 h; short s; } u; u.h = __float2bfloat16(x); return u.s;
}
__device__ __forceinline__ float expg(float d) {   // no inf/NaN path
  return (d < -80.f) ? 0.f : __expf(d);
}

// ---------------- pre-pass: fp32 -> bf16, row-major + transposed ----------
__global__ __launch_bounds__(256) void cvt_kernel(
    const float* __restrict__ X, short* __restrict__ Xb, short* __restrict__ XT)
{
  __shared__ short t[32][33];
  const int b  = blockIdx.z;
  const int n0 = blockIdx.x * 32;
  const int d0 = blockIdx.y * 32;
  const int tid = threadIdx.x;
  const int nr = tid >> 3;
  const int dc = (tid & 7) * 4;
  float4v v = *(const float4v*)(X + ((size_t)b * NN + n0 + nr) * DD + d0 + dc);
  short4v s;
  s[0] = f2bf(v[0]); s[1] = f2bf(v[1]); s[2] = f2bf(v[2]); s[3] = f2bf(v[3]);
  *(short4v*)(Xb + ((size_t)b * NN + n0 + nr) * DD + d0 + dc) = s;
  t[dc + 0][nr] = s[0]; t[dc + 1][nr] = s[1];
  t[dc + 2][nr] = s[2]; t[dc + 3][nr] = s[3];
  __syncthreads();
  const int dr = tid >> 3;
  const int nc = (tid & 7) * 4;
  short4v w;
  w[0] = t[dr][nc]; w[1] = t[dr][nc + 1]; w[2] = t[dr][nc + 2]; w[3] = t[dr][nc + 3];
  *(short4v*)(XT + ((size_t)b * DD + d0 + dr) * NN + n0 + nc) = w;
}

// ---------------- main kernel (R9) ----------------
__global__ __launch_bounds__(256, 2) void attn9(
    const short* __restrict__ Xb,   // bf16 [B][N][D]
    const short* __restrict__ XT,   // bf16 [B][D][N]
    const int*   __restrict__ adj,  // [B][N][N]
    float*       __restrict__ out)  // [B][N][D] fp32
{
  __shared__ __align__(16) char smem[SM_BYTES];
  short* Ksm  = (short*)smem;
  short* Pbuf = (short*)(smem + OFF_PBUF);
  float* Msm  = (float*)(smem + OFF_MSM);
  float* Lsm  = (float*)(smem + OFF_LSM);
  float* Osm  = (float*)smem;                 // merge phase only

  const int tid  = threadIdx.x;
  const int wave = tid >> 6;
  const int lane = tid & 63;
  const int l15  = lane & 15;
  const int quad = lane >> 4;
  const int pair = wave >> 1;     // K-half owner
  const int wq   = wave & 1;      // query 16-row sub-tile
  const int pt   = tid & 127;     // thread index within pair

  const int b  = blockIdx.x >> 6;           // N/QT = 64 q-tiles
  const int q0 = (blockIdx.x & 63) * QT;
  const int qw = q0 + wq * 16;

  const short* Xbb = Xb + (size_t)b * NN * DD;
  const short* XTb = XT + (size_t)b * DD * NN;
  short* KsmP = Ksm + pair * (KT * KSM_S);

  // Xq A-fragments: A[m=l15][k=quad*8+j]
  short8 aq[16];
  {
    const short* xrow = Xbb + (size_t)(qw + l15) * DD + quad * 8;
#pragma unroll
    for (int c = 0; c < 16; ++c) aq[c] = *(const short8*)(xrow + c * 32);
  }

  float4v o[32];
#pragma unroll
  for (int i = 0; i < 32; ++i) o[i] = (float4v){0.f, 0.f, 0.f, 0.f};
  float m_i[4] = {-1e30f, -1e30f, -1e30f, -1e30f};
  float l_i[4] = {0.f, 0.f, 0.f, 0.f};

  const int* adjq = adj + ((size_t)b * NN + qw) * NN;

  for (int kt = 0; kt < KHALF / KT; ++kt) {   // 32 tiles per pair
    const int kb = pair * KHALF + kt * KT;
    __syncthreads();  // (A) prev tile's Ksm reads done

    // stage K-tile bf16 (no cvt): 2048 short8 chunks / 128 pair-threads
#pragma unroll
    for (int it = 0; it < 16; ++it) {
      const int idx = it * 128 + pt;
      const int r = idx >> 6, c8 = idx & 63;
      *(short8*)(&KsmP[r * KSM_S + c8 * 8]) =
          *(const short8*)(Xbb + (size_t)(kb + r) * DD + c8 * 8);
    }
    __syncthreads();  // (B)

    // ---- S = Xq * Xk^T ----
    float4v s0 = {0.f, 0.f, 0.f, 0.f}, s1 = {0.f, 0.f, 0.f, 0.f};
#pragma unroll
    for (int c = 0; c < 16; ++c) {
      short8 b0 = *(const short8*)(&KsmP[l15 * KSM_S + c * 32 + quad * 8]);
      short8 b1 = *(const short8*)(&KsmP[(16 + l15) * KSM_S + c * 32 + quad * 8]);
      s0 = __builtin_amdgcn_mfma_f32_16x16x32_bf16(aq[c], b0, s0, 0, 0, 0);
      s1 = __builtin_amdgcn_mfma_f32_16x16x32_bf16(aq[c], b1, s1, 0, 0, 0);
    }

    // ---- mask + online softmax ----
#pragma unroll
    for (int r = 0; r < 4; ++r) {
      const int qr = quad * 4 + r;
      const int q  = qw + qr;
      const int* arow = adjq + (size_t)qr * NN + kb;
      float v0 = s0[r], v1 = s1[r];
      const int k0 = kb + l15, k1 = kb + 16 + l15;
      if (arow[l15]      == 0 && q != k0) v0 = NEGINF;   // adj + eye
      if (arow[16 + l15] == 0 && q != k1) v1 = NEGINF;
      float mr = fmaxf(v0, v1);
      mr = fmaxf(mr, __shfl_xor(mr, 1));
      mr = fmaxf(mr, __shfl_xor(mr, 2));
      mr = fmaxf(mr, __shfl_xor(mr, 4));
      mr = fmaxf(mr, __shfl_xor(mr, 8));
      const float mnew  = fmaxf(m_i[r], mr);
      const float alpha = expg(m_i[r] - mnew);
      m_i[r] = mnew;
      const float p0 = expg(v0 - mnew);
      const float p1 = expg(v1 - mnew);
      float rs = p0 + p1;
      rs += __shfl_xor(rs, 1);
      rs += __shfl_xor(rs, 2);
      rs += __shfl_xor(rs, 4);
      rs += __shfl_xor(rs, 8);
      l_i[r] = l_i[r] * alpha + rs;
#pragma unroll
      for (int dt = 0; dt < 32; ++dt) o[dt][r] *= alpha;
      Pbuf[(wave * 16 + qr) * PB_S + l15]      = f2bf(p0);
      Pbuf[(wave * 16 + qr) * PB_S + 16 + l15] = f2bf(p1);
    }
    __syncthreads();  // (C) Pbuf visible

    // ---- O += P * V ; V B-frags direct from XT16 (16B, L2-hot) ----
    const short8 ap = *(const short8*)(&Pbuf[(wave * 16 + l15) * PB_S + quad * 8]);
#pragma unroll
    for (int dt = 0; dt < 32; ++dt) {
      const short8 bv = *(const short8*)(XTb + (size_t)(dt * 16 + l15) * NN + kb + quad * 8);
      o[dt] = __builtin_amdgcn_mfma_f32_16x16x32_bf16(ap, bv, o[dt], 0, 0, 0);
    }
  }

  // ---- flash merge across wave pairs (wave w <-> w^2), then store ----
  __syncthreads();
  if (l15 == 0) {
#pragma unroll
    for (int r = 0; r < 4; ++r) {
      Msm[wave * 16 + quad * 4 + r] = m_i[r];
      Lsm[wave * 16 + quad * 4 + r] = l_i[r];
    }
  }
  __syncthreads();
  const int partner = wave ^ 2;
  float aw_[4];
#pragma unroll
  for (int r = 0; r < 4; ++r) {
    const float mp = Msm[partner * 16 + quad * 4 + r];
    aw_[r] = expg(m_i[r] - fmaxf(m_i[r], mp));
  }
  if (wave >= 2) {
#pragma unroll
    for (int r = 0; r < 4; ++r) {
      const int q = wq * 16 + quad * 4 + r;
#pragma unroll
      for (int dt = 0; dt < 32; ++dt)
        Osm[q * DD + dt * 16 + l15] = aw_[r] * o[dt][r];
    }
  }
  __syncthreads();
  if (wave < 2) {
#pragma unroll
    for (int r = 0; r < 4; ++r) {
      const int qr = quad * 4 + r;
      const int q  = wq * 16 + qr;
      const float mp = Msm[partner * 16 + qr];
      const float lp = Lsm[partner * 16 + qr];
      const float a1 = expg(mp - fmaxf(m_i[r], mp));
      const float inv = 1.0f / fmaxf(aw_[r] * l_i[r] + a1 * lp, 1e-30f);
      float* po = out + ((size_t)b * NN + q0 + q) * DD + l15;
#pragma unroll
      for (int dt = 0; dt < 32; ++dt)
        po[dt * 16] = (aw_[r] * o[dt][r] + Osm[q * DD + dt * 16 + l15]) * inv;
    }
  }
}

// ---------------- fallback: round-8 kernel (used if ws too small) ----------
#define KST_S 40
__device__ __forceinline__ short8 cvt8(const float* p) {
  float4v u0 = *(const float4v*)(p);
  float4v u1 = *(const float4v*)(p + 4);
  short8 v;
  v[0] = f2bf(u0[0]); v[1] = f2bf(u0[1]); v[2] = f2bf(u0[2]); v[3] = f2bf(u0[3]);
  v[4] = f2bf(u1[0]); v[5] = f2bf(u1[1]); v[6] = f2bf(u1[2]); v[7] = f2bf(u1[3]);
  return v;
}
__global__ __launch_bounds__(256, 2) void attn8(
    const float* __restrict__ X, const int* __restrict__ adj, float* __restrict__ out)
{
  __shared__ short Ksm [KT * KSM_S];
  __shared__ short KsmT[DD * KST_S];
  __shared__ short Pb8 [4 * 16 * PB_S];
  const int tid = threadIdx.x, wave = tid >> 6, lane = tid & 63;
  const int l15 = lane & 15, quad = lane >> 4;
  const int b = blockIdx.x >> 5, q0 = (blockIdx.x & 31) * 64;
  const int qw = q0 + wave * 16;
  const float* Xb = X + (size_t)b * NN * DD;
  short8 aq[16];
  {
    const float* xrow = Xb + (size_t)(qw + l15) * DD + quad * 8;
#pragma unroll
    for (int c = 0; c < 16; ++c) aq[c] = cvt8(xrow + c * 32);
  }
  float4v o[32];
#pragma unroll
  for (int i = 0; i < 32; ++i) o[i] = (float4v){0.f, 0.f, 0.f, 0.f};
  float m_i[4] = {-1e30f, -1e30f, -1e30f, -1e30f};
  float l_i[4] = {0.f, 0.f, 0.f, 0.f};
  const int* adjq = adj + ((size_t)b * NN + qw) * NN;
  for (int kt = 0; kt < NN / KT; ++kt) {
    const int kb = kt * KT;
    __syncthreads();
    {
      const int c = lane * 8;
#pragma unroll
      for (int it = 0; it < 8; ++it) {
        const int r = it * 4 + wave;
        *(short8*)(&Ksm[r * KSM_S + c]) = cvt8(Xb + (size_t)(kb + r) * DD + c);
      }
      const int rr = tid & 31, cg = (tid >> 5) * 8;
#pragma unroll
      for (int it = 0; it < 8; ++it) {
        const int col = it * 64 + cg;
        short8 v = cvt8(Xb + (size_t)(kb + rr) * DD + col);
#pragma unroll
        for (int j = 0; j < 8; ++j) KsmT[(col + j) * KST_S + rr] = v[j];
      }
    }
    __syncthreads();
    float4v s0 = {0.f,0.f,0.f,0.f}, s1 = {0.f,0.f,0.f,0.f};
#pragma unroll
    for (int c = 0; c < 16; ++c) {
      short8 b0 = *(const short8*)(&Ksm[l15 * KSM_S + c * 32 + quad * 8]);
      short8 b1 = *(const short8*)(&Ksm[(16 + l15) * KSM_S + c * 32 + quad * 8]);
      s0 = __builtin_amdgcn_mfma_f32_16x16x32_bf16(aq[c], b0, s0, 0, 0, 0);
      s1 = __builtin_amdgcn_mfma_f32_16x16x32_bf16(aq[c], b1, s1, 0, 0, 0);
    }
#pragma unroll
    for (int r = 0; r < 4; ++r) {
      const int qr = quad * 4 + r, q = qw + qr;
      const int* arow = adjq + (size_t)qr * NN + kb;
      float v0 = s0[r], v1 = s1[r];
      if (arow[l15] == 0 && q != kb + l15) v0 = NEGINF;
      if (arow[16 + l15] == 0 && q != kb + 16 + l15) v1 = NEGINF;
      float mr = fmaxf(v0, v1);
      mr = fmaxf(mr, __shfl_xor(mr, 1)); mr = fmaxf(mr, __shfl_xor(mr, 2));
      mr = fmaxf(mr, __shfl_xor(mr, 4)); mr = fmaxf(mr, __shfl_xor(mr, 8));
      const float mnew = fmaxf(m_i[r], mr);
      const float alpha = expg(m_i[r] - mnew);
      m_i[r] = mnew;
      const float p0 = expg(v0 - mnew), p1 = expg(v1 - mnew);
      float rs = p0 + p1;
      rs += __shfl_xor(rs, 1); rs += __shfl_xor(rs, 2);
      rs += __shfl_xor(rs, 4); rs += __shfl_xor(rs, 8);
      l_i[r] = l_i[r] * alpha + rs;
#pragma unroll
      for (int dt = 0; dt < 32; ++dt) o[dt][r] *= alpha;
      Pb8[(wave * 16 + qr) * PB_S + l15] = f2bf(p0);
      Pb8[(wave * 16 + qr) * PB_S + 16 + l15] = f2bf(p1);
    }
    __syncthreads();
    const short8 ap = *(const short8*)(&Pb8[(wave * 16 + l15) * PB_S + quad * 8]);
#pragma unroll
    for (int dt = 0; dt < 32; ++dt) {
      short8 bv = *(const short8*)(&KsmT[(dt * 16 + l15) * KST_S + quad * 8]);
      o[dt] = __builtin_amdgcn_mfma_f32_16x16x32_bf16(ap, bv, o[dt], 0, 0, 0);
    }
  }
#pragma unroll
  for (int r = 0; r < 4; ++r) {
    const float inv = 1.0f / fmaxf(l_i[r], 1e-30f);
    float* po = out + ((size_t)b * NN + (qw + quad * 4 + r)) * DD + l15;
#pragma unroll
    for (int dt = 0; dt < 32; ++dt) po[dt * 16] = o[dt][r] * inv;
  }
}

extern "C" void kernel_launch(void* const* d_in, const int* in_sizes, int n_in,
                              void* d_out, int out_size, void* d_ws, size_t ws_size,
                              hipStream_t stream) {
  const float* X   = (const float*)d_in[0];
  const int*   adj = (const int*)d_in[2];
  float*       out = (float*)d_out;
  const size_t elems = (size_t)NB * NN * DD;
  if (ws_size >= 2 * elems * sizeof(short)) {
    short* Xb16 = (short*)d_ws;
    short* XT16 = Xb16 + elems;
    hipLaunchKernelGGL(cvt_kernel, dim3(NN / 32, DD / 32, NB), dim3(256), 0, stream,
                       X, Xb16, XT16);
    hipLaunchKernelGGL(attn9, dim3(NB * (NN / QT)), dim3(256), 0, stream,
                       Xb16, XT16, adj, out);
  } else {
    hipLaunchKernelGGL(attn8, dim3(NB * 32), dim3(256), 0, stream, X, adj, out);
  }
}